// Round 5
// baseline (660.078 us; speedup 1.0000x reference)
//
#include <hip/hip_runtime.h>
#include <math.h>

#define D 100
#define T 50
#define BB 512
#define NOUT 99999

__device__ __forceinline__ float sigf(float x) { return 1.f / (1.f + expf(-x)); }

// ===========================================================================
// Fused per-batch GGNN + attention kernel. One block per batch (512 blocks).
// LDS: hS (h, later h'), R1 (X1 -> a_in -> r*h -> seqW), R2 (X2 -> a_out -> u)
// All weight-GEMM phases are register-tiled over t AND software-pipelined:
// ping-pong register buffers prefetch the next k-group's weight quads while
// the current group's FMAs run (L2 latency ~200 cyc vs 160-480 cyc compute;
// only 2 waves/SIMD resident, so HW can't cover it alone -> was 50% stall).
// ===========================================================================
__global__ __launch_bounds__(256) void ggnn_fused(
    const float* __restrict__ adj_in, const float* __restrict__ adj_out,
    const float* __restrict__ mask,   const int* __restrict__ item,
    const int* __restrict__ alias_,   const float* __restrict__ emb,
    const float* __restrict__ W_in,   const float* __restrict__ b_in,
    const float* __restrict__ W_out,  const float* __restrict__ b_out,
    const float* __restrict__ gate_k, const float* __restrict__ gate_b,
    const float* __restrict__ cand_k, const float* __restrict__ cand_b,
    const float* __restrict__ w1,     const float* __restrict__ w2,
    const float* __restrict__ v,      const float* __restrict__ nb,
    const float* __restrict__ Bm,     float* __restrict__ y1)
{
    __shared__ float hS[T*D];      // 20 KB
    __shared__ float R1[T*D];      // 20 KB
    __shared__ float R2[T*D];      // 20 KB
    __shared__ float maskS[T+2], vS[D], nbS[D], lastWS[D], coefS[T+2], maS[2*D];
    __shared__ int aliasS[T+2];
    __shared__ int rmidx;

    const int b = blockIdx.x, tid = threadIdx.x;
    const size_t bT = (size_t)b * T;

    // ---- P0: small stages ----
    if (tid < T) {
        aliasS[tid] = alias_[bT + tid];
        maskS[tid]  = mask[bT + tid];
    }
    if (tid >= 64 && tid < 64 + D) {
        int k = tid - 64;
        vS[k] = v[k]; nbS[k] = nb[k];
    }
    // ---- P1: h = emb[item] ----
    for (int idx = tid; idx < T*25; idx += 256) {
        int t = idx / 25, q = idx - t*25;
        int node = item[bT + t];
        *(float4*)&hS[t*D + q*4] = *(const float4*)&emb[(size_t)node*D + q*4];
    }
    __syncthreads();
    if (tid == 0) {
        float s = 0.f;
        for (int t = 0; t < T; ++t) s += maskS[t];
        rmidx = aliasS[(int)s - 1];
    }

    // role decode for the 250 active weight-GEMM threads
    const bool act250 = tid < 250;
    const int tg50  = tid / 50;      // 0..4 valid  (t-group of 10)
    const int rem50 = tid % 50;
    const int cg25  = tid / 25;      // 0..9 valid  (t-group of 5)
    const int jq25  = tid % 25;

    // ---- P2: X1 = h@W_in+b_in -> R1 ; X2 = h@W_out+b_out -> R2 ----
    // groups of 4 k; ping-pong prefetch of 4 weight quads
    if (act250) {
        const int which = rem50 / 25, jq = rem50 % 25;
        const int t0 = tg50 * 10;
        const float* W  = which ? W_out : W_in;
        const float* bb = which ? b_out : b_in;
        float4 binit = *(const float4*)&bb[jq*4];
        float4 acc[10];
        #pragma unroll
        for (int tt = 0; tt < 10; ++tt) acc[tt] = binit;

        float4 wq[4], wp[4];
#define P2_LOAD(dst, k0) { _Pragma("unroll") \
        for (int d = 0; d < 4; ++d) dst[d] = *(const float4*)&W[((k0)+d)*D + jq*4]; }
#define P2_COMP(buf, k0) { _Pragma("unroll") \
        for (int d2 = 0; d2 < 4; d2 += 2) { _Pragma("unroll") \
            for (int tt = 0; tt < 10; ++tt) { \
                float2 a = *(const float2*)&hS[(t0+tt)*D + (k0) + d2]; \
                acc[tt].x += a.x*buf[d2].x + a.y*buf[d2+1].x; \
                acc[tt].y += a.x*buf[d2].y + a.y*buf[d2+1].y; \
                acc[tt].z += a.x*buf[d2].z + a.y*buf[d2+1].z; \
                acc[tt].w += a.x*buf[d2].w + a.y*buf[d2+1].w; } } }
        P2_LOAD(wq, 0);
        #pragma unroll 1
        for (int k = 0; k < 88; k += 8) {
            P2_LOAD(wp, k+4);  P2_COMP(wq, k);
            P2_LOAD(wq, k+8);  P2_COMP(wp, k+4);
        }
        P2_LOAD(wp, 92);  P2_COMP(wq, 88);
        P2_LOAD(wq, 96);  P2_COMP(wp, 92);
        P2_COMP(wq, 96);

        float* dst = which ? R2 : R1;
        #pragma unroll
        for (int tt = 0; tt < 10; ++tt)
            *(float4*)&dst[(t0+tt)*D + jq*4] = acc[tt];
    }
    __syncthreads();

    // ---- P3: a_in = adj_in@X1, a_out = adj_out@X2 (into regs) ----
    // prefetch next adj column while current column's FMAs run
    float4 eacc[10];
    if (act250) {
        const int which = rem50 / 25, jq = rem50 % 25;
        const int t0 = tg50 * 10;
        const float* adjp = which ? adj_out : adj_in;
        const float* Xs   = which ? R2 : R1;
        const float* apb  = &adjp[(bT + t0)*T];
        float ac[10], an[10];
        #pragma unroll
        for (int tt = 0; tt < 10; ++tt) {
            eacc[tt] = make_float4(0.f,0.f,0.f,0.f);
            ac[tt] = apb[tt*T];
        }
        #pragma unroll 1
        for (int s = 0; s < T-1; ++s) {
            #pragma unroll
            for (int tt = 0; tt < 10; ++tt) an[tt] = apb[tt*T + s + 1];
            float4 x = *(const float4*)&Xs[s*D + jq*4];
            #pragma unroll
            for (int tt = 0; tt < 10; ++tt) {
                eacc[tt].x += ac[tt]*x.x; eacc[tt].y += ac[tt]*x.y;
                eacc[tt].z += ac[tt]*x.z; eacc[tt].w += ac[tt]*x.w;
                ac[tt] = an[tt];
            }
        }
        float4 x = *(const float4*)&Xs[(T-1)*D + jq*4];
        #pragma unroll
        for (int tt = 0; tt < 10; ++tt) {
            eacc[tt].x += ac[tt]*x.x; eacc[tt].y += ac[tt]*x.y;
            eacc[tt].z += ac[tt]*x.z; eacc[tt].w += ac[tt]*x.w;
        }
    }
    __syncthreads();                 // all X reads done
    // ---- P3b: write a_in -> R1, a_out -> R2 ----
    if (act250) {
        const int which = rem50 / 25, jq = rem50 % 25;
        const int t0 = tg50 * 10;
        float* dst = which ? R2 : R1;
        #pragma unroll
        for (int tt = 0; tt < 10; ++tt)
            *(float4*)&dst[(t0+tt)*D + jq*4] = eacc[tt];
    }
    __syncthreads();

    // ---- P4: gates = sigmoid([a_in|a_out|h] @ gate_k + gate_b) into regs ----
    // k-pairs; ping-pong prefetch of 6 weight quads (3 segments x 2 k)
    float4 gacc[10];
    if (act250) {
        const int nq = rem50;
        const int t0 = tg50 * 10;
        float4 ginit = *(const float4*)&gate_b[nq*4];
        #pragma unroll
        for (int tt = 0; tt < 10; ++tt) gacc[tt] = ginit;

        float4 gq6[6], gp6[6];
#define P4_LOAD(dst, kp) { _Pragma("unroll") \
        for (int s = 0; s < 3; ++s) { \
            dst[s*2]   = *(const float4*)&gate_k[(size_t)((kp)+s*100)*200 + nq*4]; \
            dst[s*2+1] = *(const float4*)&gate_k[(size_t)((kp)+1+s*100)*200 + nq*4]; } }
#define P4_COMP(buf, kp) { _Pragma("unroll") \
        for (int tt = 0; tt < 10; ++tt) { \
            float2 a0 = *(const float2*)&R1[(t0+tt)*D + (kp)]; \
            float2 a1 = *(const float2*)&R2[(t0+tt)*D + (kp)]; \
            float2 a2 = *(const float2*)&hS[(t0+tt)*D + (kp)]; \
            gacc[tt].x += a0.x*buf[0].x + a0.y*buf[1].x + a1.x*buf[2].x + a1.y*buf[3].x + a2.x*buf[4].x + a2.y*buf[5].x; \
            gacc[tt].y += a0.x*buf[0].y + a0.y*buf[1].y + a1.x*buf[2].y + a1.y*buf[3].y + a2.x*buf[4].y + a2.y*buf[5].y; \
            gacc[tt].z += a0.x*buf[0].z + a0.y*buf[1].z + a1.x*buf[2].z + a1.y*buf[3].z + a2.x*buf[4].z + a2.y*buf[5].z; \
            gacc[tt].w += a0.x*buf[0].w + a0.y*buf[1].w + a1.x*buf[2].w + a1.y*buf[3].w + a2.x*buf[4].w + a2.y*buf[5].w; } }
        P4_LOAD(gq6, 0);
        #pragma unroll 1
        for (int k = 0; k < 96; k += 4) {
            P4_LOAD(gp6, k+2);  P4_COMP(gq6, k);
            P4_LOAD(gq6, k+4);  P4_COMP(gp6, k+2);
        }
        P4_LOAD(gp6, 98);
        P4_COMP(gq6, 96);
        P4_COMP(gp6, 98);

        #pragma unroll
        for (int tt = 0; tt < 10; ++tt) {
            gacc[tt].x = sigf(gacc[tt].x); gacc[tt].y = sigf(gacc[tt].y);
            gacc[tt].z = sigf(gacc[tt].z); gacc[tt].w = sigf(gacc[tt].w);
        }
    }

    // ---- P5a: cand partial (segments a_in, a_out) into regs ----
    // groups of 4 k; ping-pong prefetch of 8 quads (2 segments x 4 k)
    float4 cacc[5];
    if (act250) {
        const int t0 = cg25 * 5;
        float4 cinit = *(const float4*)&cand_b[jq25*4];
        #pragma unroll
        for (int tt = 0; tt < 5; ++tt) cacc[tt] = cinit;

        float4 cq[8], cp[8];
#define P5A_LOAD(dst, k0) { _Pragma("unroll") \
        for (int s = 0; s < 2; ++s) { _Pragma("unroll") \
            for (int d = 0; d < 4; ++d) \
                dst[s*4+d] = *(const float4*)&cand_k[(size_t)((k0)+d+s*100)*D + jq25*4]; } }
#define P5A_COMP(buf, k0) { _Pragma("unroll") \
        for (int d2 = 0; d2 < 4; d2 += 2) { _Pragma("unroll") \
            for (int tt = 0; tt < 5; ++tt) { \
                float2 a0 = *(const float2*)&R1[(t0+tt)*D + (k0)+d2]; \
                float2 a1 = *(const float2*)&R2[(t0+tt)*D + (k0)+d2]; \
                cacc[tt].x += a0.x*buf[d2].x + a0.y*buf[d2+1].x + a1.x*buf[4+d2].x + a1.y*buf[4+d2+1].x; \
                cacc[tt].y += a0.x*buf[d2].y + a0.y*buf[d2+1].y + a1.x*buf[4+d2].y + a1.y*buf[4+d2+1].y; \
                cacc[tt].z += a0.x*buf[d2].z + a0.y*buf[d2+1].z + a1.x*buf[4+d2].z + a1.y*buf[4+d2+1].z; \
                cacc[tt].w += a0.x*buf[d2].w + a0.y*buf[d2+1].w + a1.x*buf[4+d2].w + a1.y*buf[4+d2+1].w; } } }
        P5A_LOAD(cq, 0);
        #pragma unroll 1
        for (int k = 0; k < 88; k += 8) {
            P5A_LOAD(cp, k+4);  P5A_COMP(cq, k);
            P5A_LOAD(cq, k+8);  P5A_COMP(cp, k+4);
        }
        P5A_LOAD(cp, 92);  P5A_COMP(cq, 88);
        P5A_LOAD(cq, 96);  P5A_COMP(cp, 92);
        P5A_COMP(cq, 96);
    }
    __syncthreads();                 // R1/R2 (a_in/a_out) reads done

    // ---- P5b: r-owners write r*h -> R1 ; u-owners write u -> R2 ----
    if (act250) {
        const int nq = rem50;
        const int t0 = tg50 * 10;
        if (nq < 25) {
            #pragma unroll
            for (int tt = 0; tt < 10; ++tt) {
                float4 hh = *(const float4*)&hS[(t0+tt)*D + nq*4];
                float4 g = gacc[tt];
                float4 o; o.x = g.x*hh.x; o.y = g.y*hh.y; o.z = g.z*hh.z; o.w = g.w*hh.w;
                *(float4*)&R1[(t0+tt)*D + nq*4] = o;
            }
        } else {
            #pragma unroll
            for (int tt = 0; tt < 10; ++tt)
                *(float4*)&R2[(t0+tt)*D + (nq-25)*4] = gacc[tt];
        }
    }
    __syncthreads();

    // ---- P5c: cand segment r*h + tanh; fused P7: h' = u*h+(1-u)*c -> hS ----
    // groups of 4 k; ping-pong prefetch of 4 quads
    if (act250) {
        const int t0 = cg25 * 5;
        float4 dq[4], dp[4];
#define P5C_LOAD(dst, k0) { _Pragma("unroll") \
        for (int d = 0; d < 4; ++d) \
            dst[d] = *(const float4*)&cand_k[(size_t)((k0)+d+200)*D + jq25*4]; }
#define P5C_COMP(buf, k0) { _Pragma("unroll") \
        for (int d2 = 0; d2 < 4; d2 += 2) { _Pragma("unroll") \
            for (int tt = 0; tt < 5; ++tt) { \
                float2 rh = *(const float2*)&R1[(t0+tt)*D + (k0)+d2]; \
                cacc[tt].x += rh.x*buf[d2].x + rh.y*buf[d2+1].x; \
                cacc[tt].y += rh.x*buf[d2].y + rh.y*buf[d2+1].y; \
                cacc[tt].z += rh.x*buf[d2].z + rh.y*buf[d2+1].z; \
                cacc[tt].w += rh.x*buf[d2].w + rh.y*buf[d2+1].w; } } }
        P5C_LOAD(dq, 0);
        #pragma unroll 1
        for (int k = 0; k < 88; k += 8) {
            P5C_LOAD(dp, k+4);  P5C_COMP(dq, k);
            P5C_LOAD(dq, k+8);  P5C_COMP(dp, k+4);
        }
        P5C_LOAD(dp, 92);  P5C_COMP(dq, 88);
        P5C_LOAD(dq, 96);  P5C_COMP(dp, 92);
        P5C_COMP(dq, 96);

        #pragma unroll
        for (int tt = 0; tt < 5; ++tt) {
            float4 c4;
            c4.x = tanhf(cacc[tt].x); c4.y = tanhf(cacc[tt].y);
            c4.z = tanhf(cacc[tt].z); c4.w = tanhf(cacc[tt].w);
            float4 u4 = *(const float4*)&R2[(t0+tt)*D + jq25*4];
            float4 hh = *(const float4*)&hS[(t0+tt)*D + jq25*4];
            float4 o;
            o.x = u4.x*hh.x + (1.f-u4.x)*c4.x;
            o.y = u4.y*hh.y + (1.f-u4.y)*c4.y;
            o.z = u4.z*hh.z + (1.f-u4.z)*c4.z;
            o.w = u4.w*hh.w + (1.f-u4.w)*c4.w;
            *(float4*)&hS[(t0+tt)*D + jq25*4] = o;
        }
    }
    __syncthreads();

    // ---- P8: seqW[t] = h'[alias[t]] @ w2 -> R1 ; lastW = h'[rmidx] @ w1 ----
    if (tid < 125) {
        const int sg = tid / 25, jq = tid % 25;
        const int t0 = sg * 10;
        float4 sacc[10];
        #pragma unroll
        for (int tt = 0; tt < 10; ++tt) sacc[tt] = make_float4(0.f,0.f,0.f,0.f);
        int at[10];
        #pragma unroll
        for (int tt = 0; tt < 10; ++tt) at[tt] = aliasS[t0+tt];

        float4 wq[4], wp[4];
#define P8_LOAD(dst, k0) { _Pragma("unroll") \
        for (int d = 0; d < 4; ++d) dst[d] = *(const float4*)&w2[(size_t)((k0)+d)*D + jq*4]; }
#define P8_COMP(buf, k0) { _Pragma("unroll") \
        for (int d2 = 0; d2 < 4; d2 += 2) { _Pragma("unroll") \
            for (int tt = 0; tt < 10; ++tt) { \
                float2 a = *(const float2*)&hS[at[tt]*D + (k0) + d2]; \
                sacc[tt].x += a.x*buf[d2].x + a.y*buf[d2+1].x; \
                sacc[tt].y += a.x*buf[d2].y + a.y*buf[d2+1].y; \
                sacc[tt].z += a.x*buf[d2].z + a.y*buf[d2+1].z; \
                sacc[tt].w += a.x*buf[d2].w + a.y*buf[d2+1].w; } } }
        P8_LOAD(wq, 0);
        #pragma unroll 1
        for (int k = 0; k < 88; k += 8) {
            P8_LOAD(wp, k+4);  P8_COMP(wq, k);
            P8_LOAD(wq, k+8);  P8_COMP(wp, k+4);
        }
        P8_LOAD(wp, 92);  P8_COMP(wq, 88);
        P8_LOAD(wq, 96);  P8_COMP(wp, 92);
        P8_COMP(wq, 96);

        #pragma unroll
        for (int tt = 0; tt < 10; ++tt)
            *(float4*)&R1[(t0+tt)*D + jq*4] = sacc[tt];
    } else if (tid >= 128 && tid < 153) {
        const int jq = tid - 128;
        const int lid = rmidx;
        float4 acc = make_float4(0.f,0.f,0.f,0.f);
        for (int k = 0; k < D; k += 2) {
            float4 wa = *(const float4*)&w1[(size_t)k*D + jq*4];
            float4 wb = *(const float4*)&w1[(size_t)(k+1)*D + jq*4];
            float2 a = *(const float2*)&hS[lid*D + k];
            acc.x += a.x*wa.x + a.y*wb.x;
            acc.y += a.x*wa.y + a.y*wb.y;
            acc.z += a.x*wa.z + a.y*wb.z;
            acc.w += a.x*wa.w + a.y*wb.w;
        }
        *(float4*)&lastWS[jq*4] = acc;
    }
    __syncthreads();

    // ---- P9: coef[t] = mask[t] * sum_k v[k]*sigmoid(lastW[k]+seqW[t][k]+nb[k])
    if (tid < T) {
        float s = 0.f;
        #pragma unroll 4
        for (int k = 0; k < D; ++k) {
            float x = lastWS[k] + R1[tid*D + k] + nbS[k];
            s += vS[k] * sigf(x);
        }
        coefS[tid] = s * maskS[tid];
    }
    __syncthreads();
    // ---- P10: ma = [sum_t coef[t]*h'[alias[t]], lastW] ----
    if (tid < 25) {
        float4 acc = make_float4(0.f,0.f,0.f,0.f);
        #pragma unroll 5
        for (int t = 0; t < T; ++t) {
            float c = coefS[t];
            float4 hh = *(const float4*)&hS[aliasS[t]*D + tid*4];
            acc.x += c*hh.x; acc.y += c*hh.y; acc.z += c*hh.z; acc.w += c*hh.w;
        }
        *(float4*)&maS[tid*4] = acc;
    } else if (tid >= 32 && tid < 57) {
        int j4 = tid - 32;
        *(float4*)&maS[D + j4*4] = *(const float4*)&lastWS[j4*4];
    }
    __syncthreads();
    // ---- P11: y1[b] = ma @ B_mat ----
    if (tid < 25) {
        float4 acc = make_float4(0.f,0.f,0.f,0.f);
        #pragma unroll 4
        for (int k = 0; k < 2*D; ++k) {
            float a = maS[k];
            float4 w = *(const float4*)&Bm[(size_t)k*D + tid*4];
            acc.x += a*w.x; acc.y += a*w.y; acc.z += a*w.z; acc.w += a*w.w;
        }
        *(float4*)&y1[(size_t)b*D + tid*4] = acc;
    }
}

// ===========================================================================
// logits[512, 99999] = y1[512,100] @ emb[1:,:]^T
// B-stationary: one block per 128-col n-tile x 256-row m-half; B tile staged
// once (52.8 KB LDS), 2 m-chunks of 128 rows; A (y1) from L2 broadcast loads.
// Bs columns stored PERMUTED: col (h*64 + j*16 + tx) at slot (h*64 + tx*4 + j)
// so each thread's 8 owned columns are two ds_read_b128 (was 8 scalar reads
// per kk -> 4x fewer LDS issue cycles), while stores keep the 64 B-contiguous
// {tx,+16,+32,+48} instruction pattern (float4 stores impossible: NOUT=99999
// makes 3/4 of out rows 16B-misaligned).
// ===========================================================================
#define LDB 132   // divisible by 4 -> b128-aligned rows; 52.8 KB total

#define GB_COMPUTE(Ab, kbase) do {                                            \
    _Pragma("unroll")                                                         \
    for (int kk = 0; kk < 4; ++kk) {                                          \
        float4 b0 = *(const float4*)&Bs[(kbase + kk)*LDB + tx*4];             \
        float4 b1 = *(const float4*)&Bs[(kbase + kk)*LDB + 64 + tx*4];        \
        _Pragma("unroll")                                                     \
        for (int i = 0; i < 8; ++i) {                                         \
            float a_ = kk==0 ? Ab[i].x : kk==1 ? Ab[i].y :                    \
                       kk==2 ? Ab[i].z : Ab[i].w;                             \
            acc[i][0] += a_*b0.x; acc[i][1] += a_*b0.y;                       \
            acc[i][2] += a_*b0.z; acc[i][3] += a_*b0.w;                       \
            acc[i][4] += a_*b1.x; acc[i][5] += a_*b1.y;                       \
            acc[i][6] += a_*b1.z; acc[i][7] += a_*b1.w;                       \
        }                                                                     \
    }                                                                         \
} while (0)

__global__ __launch_bounds__(256) void gemm_big(
    const float* __restrict__ y1,
    const float* __restrict__ emb,
    float* __restrict__ out)
{
    __shared__ float Bs[100*LDB];          // 52.8 KB
    const int tid = threadIdx.x;
    const int tx = tid & 15, ty = tid >> 4;
    const int n0 = blockIdx.x * 128;

    // stage B: cols n0..n0+127, k=0..99, transposed + column-permuted
    for (int idx = tid; idx < 128*25; idx += 256) {
        int n = idx / 25, q = idx - n*25;
        int gn = n0 + n;
        float4 vv = make_float4(0.f,0.f,0.f,0.f);
        if (gn < NOUT) vv = *(const float4*)&emb[(size_t)(gn+1)*D + q*4];
        int w = n & 63;
        int pos = (n & 64) + ((w & 15) << 2) + (w >> 4);
        Bs[(q*4+0)*LDB + pos] = vv.x;
        Bs[(q*4+1)*LDB + pos] = vv.y;
        Bs[(q*4+2)*LDB + pos] = vv.z;
        Bs[(q*4+3)*LDB + pos] = vv.w;
    }
    __syncthreads();

    float acc[8][8];
    float4 A0[8], A1[8];

    #pragma unroll 1
    for (int mc = 0; mc < 2; ++mc) {
        const int m0 = blockIdx.y * 256 + mc * 128;

        #pragma unroll
        for (int i = 0; i < 8; ++i)
            #pragma unroll
            for (int j = 0; j < 8; ++j) acc[i][j] = 0.f;

        #pragma unroll
        for (int i = 0; i < 8; ++i)
            A0[i] = *(const float4*)&y1[(size_t)(m0 + ty + i*16)*D + 0];

        int k = 0;
        #pragma unroll 1
        for (int it = 0; it < 12; ++it, k += 8) {
            #pragma unroll
            for (int i = 0; i < 8; ++i)
                A1[i] = *(const float4*)&y1[(size_t)(m0 + ty + i*16)*D + k + 4];
            GB_COMPUTE(A0, k);
            #pragma unroll
            for (int i = 0; i < 8; ++i)
                A0[i] = *(const float4*)&y1[(size_t)(m0 + ty + i*16)*D + k + 8];
            GB_COMPUTE(A1, k + 4);
        }
        GB_COMPUTE(A0, 96);   // k = 96..99 tail

        // store: each instr = 16 consecutive lanes -> 64 B contiguous/row
        #pragma unroll
        for (int i = 0; i < 8; ++i) {
            size_t row = (size_t)(m0 + ty + i*16) * NOUT;
            #pragma unroll
            for (int h = 0; h < 2; ++h)
                #pragma unroll
                for (int q = 0; q < 4; ++q) {
                    int n = n0 + h*64 + q*16 + tx;
                    if (n < NOUT) out[row + n] = acc[i][h*4+q];
                }
        }
    }
}

// ---------------------------------------------------------------------------
extern "C" void kernel_launch(void* const* d_in, const int* in_sizes, int n_in,
                              void* d_out, int out_size, void* d_ws, size_t ws_size,
                              hipStream_t stream)
{
    const float* adj_in  = (const float*)d_in[0];
    const float* adj_out = (const float*)d_in[1];
    const float* mask    = (const float*)d_in[2];
    const int*   item    = (const int*)  d_in[3];
    const int*   alias_  = (const int*)  d_in[4];
    const float* emb     = (const float*)d_in[6];
    const float* W_in    = (const float*)d_in[7];
    const float* b_in    = (const float*)d_in[8];
    const float* W_out   = (const float*)d_in[9];
    const float* b_out   = (const float*)d_in[10];
    const float* gate_k  = (const float*)d_in[11];
    const float* gate_b  = (const float*)d_in[12];
    const float* cand_k  = (const float*)d_in[13];
    const float* cand_b  = (const float*)d_in[14];
    const float* w1      = (const float*)d_in[15];
    const float* w2      = (const float*)d_in[16];
    const float* v       = (const float*)d_in[17];
    const float* nb      = (const float*)d_in[18];
    const float* Bm      = (const float*)d_in[19];
    float* out = (float*)d_out;
    float* y1  = (float*)d_ws;   // [512,100]

    ggnn_fused<<<BB, 256, 0, stream>>>(
        adj_in, adj_out, mask, item, alias_, emb,
        W_in, b_in, W_out, b_out, gate_k, gate_b, cand_k, cand_b,
        w1, w2, v, nb, Bm, y1);

    gemm_big<<<dim3((NOUT + 127)/128, 2), 256, 0, stream>>>(y1, emb, out);
}